// Round 1
// baseline (289.824 us; speedup 1.0000x reference)
//
#include <hip/hip_runtime.h>
#include <stdint.h>

#define HW   50176
#define IMW  224
#define NS   4096
#define EPSF 1e-6f

// ---------------- helpers ----------------
__device__ __forceinline__ bool finitef(float x){
  return (__float_as_uint(x) & 0x7f800000u) != 0x7f800000u;
}
__device__ __forceinline__ uint32_t ordenc(float f){
  uint32_t u = __float_as_uint(f);
  return (u & 0x80000000u) ? ~u : (u | 0x80000000u);
}
__device__ __forceinline__ float orddec(uint32_t e){
  uint32_t u = (e & 0x80000000u) ? (e & 0x7fffffffu) : ~e;
  return __uint_as_float(u);
}

__device__ __forceinline__ int wsum_i(int v){
  #pragma unroll
  for (int o=32;o;o>>=1) v += __shfl_down(v,o);
  return v;
}
__device__ __forceinline__ float wsum_f(float v){
  #pragma unroll
  for (int o=32;o;o>>=1) v += __shfl_down(v,o);
  return v;
}
__device__ __forceinline__ uint32_t wmin_u(uint32_t v){
  #pragma unroll
  for (int o=32;o;o>>=1){ uint32_t t=__shfl_down(v,o); v = t<v ? t : v; }
  return v;
}

__device__ __forceinline__ int block_sum_i(int v, int* lds){
  v = wsum_i(v);
  int nw = blockDim.x >> 6;
  __syncthreads();
  if ((threadIdx.x & 63)==0) lds[threadIdx.x>>6] = v;
  __syncthreads();
  if (threadIdx.x==0){ int s=0; for (int k=0;k<nw;k++) s+=lds[k]; lds[16]=s; }
  __syncthreads();
  return lds[16];
}
__device__ __forceinline__ float block_sum_f(float v, float* lds){
  v = wsum_f(v);
  int nw = blockDim.x >> 6;
  __syncthreads();
  if ((threadIdx.x & 63)==0) lds[threadIdx.x>>6] = v;
  __syncthreads();
  if (threadIdx.x==0){ float s=0.f; for (int k=0;k<nw;k++) s+=lds[k]; lds[16]=s; }
  __syncthreads();
  return lds[16];
}
__device__ __forceinline__ uint32_t block_min_u(uint32_t v, uint32_t* lds){
  v = wmin_u(v);
  int nw = blockDim.x >> 6;
  __syncthreads();
  if ((threadIdx.x & 63)==0) lds[threadIdx.x>>6] = v;
  __syncthreads();
  if (threadIdx.x==0){ uint32_t s=0xFFFFFFFFu; for (int k=0;k<nw;k++){ uint32_t t=lds[k]; s = t<s ? t:s; } lds[16]=s; }
  __syncthreads();
  return lds[16];
}

// Workspace float layout:
// [0] pose_loss  [1] depth_abs_sum  [2] mask_total  [3] normal_sum
// [4..7] pg_sum[f]  [8..11] gp_sum[f]  [12..15] selwsum[f]
// [16..19] maskcnt[f]  [20..23] scale[f]  [24..27] selcnt[f] (int)
// [32..79] relgt[f][12]  (R row-major 9, then t 3)
// [128..16511]      SEL  (int, 4*4096)
// [16512..82047]    PS   (float4, 4*4096)
// [82048..147583]   GS   (float4, 4*4096)
// [147584..180351]  RMIN (uint32 ordered-float, 2*4*4096)
#define OFF_SEL  128
#define OFF_PS   16512
#define OFF_GS   82048
#define OFF_RMIN 147584

// ---------------- init ----------------
__global__ void k_init(float* W){
  int gid = blockIdx.x*256 + threadIdx.x;           // 32768 threads
  ((uint32_t*)(W + OFF_RMIN))[gid] = 0xFF800000u;   // ordenc(+inf)
  if (gid < 128) W[gid] = 0.f;
}

// ---------------- pose (single thread) ----------------
__device__ void inv4(const float* A, float* out){
  float M[4][8];
  for (int i=0;i<4;i++) for (int j=0;j<4;j++){ M[i][j]=A[i*4+j]; M[i][4+j]=(i==j)?1.f:0.f; }
  for (int c=0;c<4;c++){
    int piv=c; float mx=fabsf(M[c][c]);
    for (int r=c+1;r<4;r++){ float a=fabsf(M[r][c]); if (a>mx){ mx=a; piv=r; } }
    if (piv!=c) for (int j=0;j<8;j++){ float t=M[c][j]; M[c][j]=M[piv][j]; M[piv][j]=t; }
    float inv = 1.f/M[c][c];
    for (int j=0;j<8;j++) M[c][j]*=inv;
    for (int r=0;r<4;r++){
      if (r==c) continue;
      float fv = M[r][c];
      for (int j=0;j<8;j++) M[r][j] -= fv*M[c][j];
    }
  }
  for (int i=0;i<4;i++) for (int j=0;j<4;j++) out[i*4+j]=M[i][4+j];
}
__device__ void mat4(const float* A, const float* B, float* C){
  for (int i=0;i<4;i++) for (int j=0;j<4;j++){
    float s=0.f;
    for (int k=0;k<4;k++) s += A[i*4+k]*B[k*4+j];
    C[i*4+j]=s;
  }
}
__global__ void k_pose(const float* pp, const float* pg, float* W){
  if (threadIdx.x!=0 || blockIdx.x!=0) return;
  float i0p[16], i0g[16];
  inv4(pp, i0p); inv4(pg, i0g);
  float s=0.f;
  for (int f=0; f<4; f++){
    float rp[16], rg[16];
    mat4(i0p, pp+16*f, rp);
    mat4(i0g, pg+16*f, rg);
    for (int k=0;k<16;k++) s += fabsf(rp[k]-rg[k]);
    for (int i=0;i<3;i++) for (int j=0;j<3;j++) W[32+f*12+i*3+j]=rg[i*4+j];
    for (int i=0;i<3;i++) W[32+f*12+9+i]=rg[i*4+3];
  }
  W[0] = s/64.f;
}

// ---------------- median + selection (one block per frame) ----------------
__global__ __launch_bounds__(1024) void k_medsel(const float* dp_, const float* dg_, float* W){
  const int f = blockIdx.x;
  const int tid = threadIdx.x;
  const float* dp = dp_ + f*HW;
  const float* dg = dg_ + f*HW;
  __shared__ int ilds[17];
  __shared__ uint32_t ulds[17];

  uint32_t rb[49];
  unsigned long long mbits = 0ull;
  int nn_l=0, mc_l=0;
  #pragma unroll
  for (int j=0;j<49;++j){
    int i = j*1024 + tid;
    float dgv = dg[i], dpv = dp[i];
    bool mg = (dgv > EPSF) && finitef(dgv);              // gt mask (>0, finite, >DEPTH_MIN)
    bool m  = mg && finitef(dpv) && (dpv > EPSF);        // ratio mask
    mc_l += mg ? 1 : 0;
    if (mg) mbits |= (1ull<<j);
    if (m){ rb[j] = __float_as_uint(dpv / fmaxf(dgv, EPSF)); nn_l++; }
    else  rb[j] = 0xFFFFFFFFu;
  }
  int nn = block_sum_i(nn_l, ilds);
  int mc = block_sum_i(mc_l, ilds);

  float scale = 1.f;
  if (nn > 0){
    int k1 = (nn-1)>>1, k2 = nn>>1;
    uint32_t lo=0u, hi=0x7F800000u;
    while (lo < hi){
      uint32_t mid = lo + ((hi-lo)>>1);
      int c_l=0;
      #pragma unroll
      for (int j=0;j<49;++j) c_l += (rb[j] <= mid) ? 1 : 0;
      int c = block_sum_i(c_l, ilds);
      if (c >= k1+1) hi = mid; else lo = mid+1;
    }
    uint32_t v1 = lo;
    int cle_l=0; uint32_t mg_l=0xFFFFFFFFu;
    #pragma unroll
    for (int j=0;j<49;++j){
      uint32_t u = rb[j];
      cle_l += (u <= v1) ? 1 : 0;
      if (u > v1 && u <= 0x7F800000u) mg_l = u < mg_l ? u : mg_l;
    }
    int cle = block_sum_i(cle_l, ilds);
    uint32_t mgt = block_min_u(mg_l, ulds);
    uint32_t v2 = (cle > k2) ? v1 : mgt;
    float med = 0.5f*(__uint_as_float(v1) + __uint_as_float(v2));
    scale = (nn < 16 || !finitef(med)) ? 1.f : fminf(fmaxf(med, 1e-3f), 1e3f);
  }
  if (tid==0){
    W[20+f] = scale;
    W[16+f] = (float)mc;
    atomicAdd(&W[2], (float)mc);
  }

  // ---- top-k selection: key = (mask<<20) | jitter_int, all keys distinct ----
  const int target = HW - NS;        // threshold = target-th smallest (0-indexed)
  uint32_t lo=0u, hi=0x1FFFFFu;
  while (lo < hi){
    uint32_t mid = lo + ((hi-lo)>>1);
    int c_l=0;
    #pragma unroll
    for (int j=0;j<49;++j){
      uint32_t i = (uint32_t)(j*1024 + tid);
      uint32_t key = ((i*2654435761u) & 0xFFFFFu) | ((uint32_t)((mbits>>j)&1ull) << 20);
      c_l += (key <= mid) ? 1 : 0;
    }
    int c = block_sum_i(c_l, ilds);
    if (c >= target+1) hi = mid; else lo = mid+1;
  }
  uint32_t TL = lo;
  int* SEL = (int*)(W + OFF_SEL);
  int* cnt = ((int*)(W + 24)) + f;
  #pragma unroll
  for (int j=0;j<49;++j){
    uint32_t i = (uint32_t)(j*1024 + tid);
    uint32_t key = ((i*2654435761u) & 0xFFFFFu) | ((uint32_t)((mbits>>j)&1ull) << 20);
    bool sel = key >= TL;
    unsigned long long ball = __ballot(sel);
    if (sel){
      int lane = tid & 63;
      int myoff = __popcll(ball & ((1ull<<lane)-1ull));
      int leader = __builtin_ctzll(ball);
      int base = 0;
      if (lane == leader) base = atomicAdd(cnt, __popcll(ball));
      base = __shfl(base, leader);
      SEL[(f<<12) + base + myoff] = (int)i;
    }
  }
}

// ---------------- gather selected pred/gt world points ----------------
__global__ __launch_bounds__(256) void k_gather(const float* points_pred, const float* depth_gt,
                                                const float* intr, float* W){
  int gid = blockIdx.x*256 + threadIdx.x;      // 16384
  int f = gid >> 12;
  const int* SEL = (const int*)(W + OFF_SEL);
  int idx = SEL[gid];
  float dgv = depth_gt[f*HW + idx];
  bool mg = (dgv > EPSF) && finitef(dgv);
  float wv = mg ? 1.f : 0.f;

  const float* p = points_pred + (size_t)(f*HW + idx)*3;
  float4 ps; ps.x=p[0]; ps.y=p[1]; ps.z=p[2]; ps.w=wv;
  ((float4*)(W + OFF_PS))[gid] = ps;

  float sc = W[20+f];
  float d = dgv * sc;
  float fx = fmaxf(intr[f*9+0], EPSF), fy = fmaxf(intr[f*9+4], EPSF);
  float cx = intr[f*9+2], cy = intr[f*9+5];
  int y = idx / IMW, x = idx - y*IMW;
  float X = ((float)x - cx)/fx * d;
  float Y = ((float)y - cy)/fy * d;
  float Z = d;
  const float* R = W + 32 + f*12;
  float4 gs;
  gs.x = R[0]*X + R[1]*Y + R[2]*Z + R[9];
  gs.y = R[3]*X + R[4]*Y + R[5]*Z + R[10];
  gs.z = R[6]*X + R[7]*Y + R[8]*Z + R[11];
  gs.w = wv;
  ((float4*)(W + OFF_GS))[gid] = gs;

  float wsum = wsum_f(wv);
  if ((threadIdx.x & 63) == 0) atomicAdd(&W[12+f], wsum);
}

// ---------------- chamfer row-min (both directions) ----------------
__global__ __launch_bounds__(256) void k_cham(float* W){
  const int f = blockIdx.y, dir = blockIdx.z;
  const int rc = blockIdx.x & 7, gc = blockIdx.x >> 3;
  const float4* PS = (const float4*)(W + OFF_PS);
  const float4* GS = (const float4*)(W + OFF_GS);
  const float4* A = dir ? GS : PS;
  const float4* B = dir ? PS : GS;
  uint32_t* RM = (uint32_t*)(W + OFF_RMIN) + dir*16384 + (f<<12);

  __shared__ float4 tile[512];
  int tid = threadIdx.x;
  for (int j=tid; j<512; j+=256){
    float4 b = B[(f<<12) + (gc<<9) + j];
    float gg = b.x*b.x + b.y*b.y + b.z*b.z;
    tile[j] = make_float4(b.x, b.y, b.z, (b.w > 0.f) ? gg : -1.f);
  }
  __syncthreads();

  int r0 = (rc<<9) + tid, r1 = r0 + 256;
  float4 a0 = A[(f<<12)+r0], a1 = A[(f<<12)+r1];
  float pp0 = a0.x*a0.x + a0.y*a0.y + a0.z*a0.z;
  float pp1 = a1.x*a1.x + a1.y*a1.y + a1.z*a1.z;
  float m0 = INFINITY, m1 = INFINITY;
  #pragma unroll 8
  for (int j=0;j<512;++j){
    float4 g = tile[j];
    float dt0 = fmaf(a0.x,g.x, fmaf(a0.y,g.y, a0.z*g.z));
    float dt1 = fmaf(a1.x,g.x, fmaf(a1.y,g.y, a1.z*g.z));
    if (g.w >= 0.f){
      m0 = fminf(m0, fmaf(-2.f, dt0, pp0 + g.w));
      m1 = fminf(m1, fmaf(-2.f, dt1, pp1 + g.w));
    }
  }
  atomicMin(&RM[r0], ordenc(m0));
  atomicMin(&RM[r1], ordenc(m1));
}

// ---------------- chamfer finish: sqrt + weighted sum ----------------
__global__ __launch_bounds__(256) void k_chamfin(float* W){
  __shared__ float flds[17];
  int gid = blockIdx.x*256 + threadIdx.x;      // 32768
  int dir = gid >> 14;
  int rem = gid & 16383;
  int f = rem >> 12;
  int row = rem & 4095;
  float val = orddec(((uint32_t*)(W + OFF_RMIN))[gid]);
  float d = isinf(val) ? 1e9f : sqrtf(fmaxf(val, 1e-12f));
  const float4* A = dir ? (const float4*)(W + OFF_GS) : (const float4*)(W + OFF_PS);
  float w = A[(f<<12)+row].w;
  float c = block_sum_f(d*w, flds);
  if (threadIdx.x==0) atomicAdd(&W[4 + dir*4 + f], c);
}

// ---------------- normals + depth L1 (fused) ----------------
__device__ __forceinline__ float3 normal_at(const float* D, float sc, int x, int y,
                                            float cx, float cy, float fx, float fy){
  int base = y*IMW + x;
  float dL = D[base-1]*sc,   dR = D[base+1]*sc;
  float dU = D[base-IMW]*sc, dD = D[base+IMW]*sc;
  float xl = ((float)(x-1)-cx)/fx, xr = ((float)(x+1)-cx)/fx, xc = ((float)x-cx)/fx;
  float yu = ((float)(y-1)-cy)/fy, yd = ((float)(y+1)-cy)/fy, yc = ((float)y-cy)/fy;
  // fy_diff = P(y+1,x) - P(y-1,x) ; fx_diff = P(y,x+1) - P(y,x-1)
  float ax = xc*dD - xc*dU, ay = yd*dD - yu*dU, az = dD - dU;
  float bx = xr*dR - xl*dL, by = yc*dR - yc*dL, bz = dR - dL;
  // cross(fy_diff, fx_diff)
  float nx = ay*bz - az*by;
  float ny = az*bx - ax*bz;
  float nz = ax*by - ay*bx;
  float l = sqrtf(nx*nx + ny*ny + nz*nz);
  float inv = 1.f/fmaxf(l, EPSF);
  return make_float3(nx*inv, ny*inv, nz*inv);
}

__global__ __launch_bounds__(256) void k_normdep(const float* dp_, const float* dg_,
                                                 const float* intr, float* W){
  __shared__ float flds[17];
  int gid = blockIdx.x*256 + threadIdx.x;      // 200704
  int f = gid / HW;
  int r = gid - f*HW;
  int y = r / IMW, x = r - y*IMW;
  float dgv = dg_[gid], dpv = dp_[gid];
  bool mg = (dgv > EPSF) && finitef(dgv);
  float mv = mg ? 1.f : 0.f;
  float sc = W[20+f];
  float dsum = fabsf(dpv - dgv*sc) * mv;

  float nsum;
  if (x > 0 && x < IMW-1 && y > 0 && y < IMW-1){
    float fx = fmaxf(intr[f*9+0], EPSF), fy = fmaxf(intr[f*9+4], EPSF);
    float cx = intr[f*9+2], cy = intr[f*9+5];
    float3 n1 = normal_at(dp_ + f*HW, 1.f, x, y, cx, cy, fx, fy);
    float3 n2 = normal_at(dg_ + f*HW, sc,  x, y, cx, cy, fx, fy);
    float l1 = sqrtf(n1.x*n1.x + n1.y*n1.y + n1.z*n1.z);
    float l2 = sqrtf(n2.x*n2.x + n2.y*n2.y + n2.z*n2.z);
    float i1 = 1.f/fmaxf(l1, EPSF), i2 = 1.f/fmaxf(l2, EPSF);
    float cosv = (n1.x*n2.x + n1.y*n2.y + n1.z*n2.z)*i1*i2;
    cosv = fminf(fmaxf(cosv, -1.f), 1.f);
    nsum = (1.f - cosv) * mv;
  } else {
    nsum = mv;    // border: both normals are zero -> cos=0 -> (1-0)*mask
  }
  float ds = block_sum_f(dsum, flds);
  float ns = block_sum_f(nsum, flds);
  if (threadIdx.x==0){
    atomicAdd(&W[1], ds);
    atomicAdd(&W[3], ns);
  }
}

// ---------------- final combine ----------------
__global__ void k_final(const float* W, float* out){
  if (threadIdx.x!=0 || blockIdx.x!=0) return;
  float md = fmaxf(W[2], 1.f);
  float depth_loss = W[1]/md;
  float normal_loss = W[3]/md;
  float cds=0.f, oks=0.f;
  for (int f=0; f<4; f++){
    if (W[16+f] >= 10.f){
      float denom = fmaxf(W[12+f], 1.f);
      cds += W[4+f]/denom + W[8+f]/denom;
      oks += 1.f;
    }
  }
  float points_loss = cds / fmaxf(oks, 1.f);
  out[0] = W[0] + depth_loss + points_loss + normal_loss;
}

extern "C" void kernel_launch(void* const* d_in, const int* in_sizes, int n_in,
                              void* d_out, int out_size, void* d_ws, size_t ws_size,
                              hipStream_t stream){
  const float* depth_pred  = (const float*)d_in[0];
  const float* points_pred = (const float*)d_in[1];
  const float* depth_gt    = (const float*)d_in[2];
  const float* intr        = (const float*)d_in[3];
  const float* pose_pred   = (const float*)d_in[4];
  const float* pose_gt     = (const float*)d_in[5];
  float* out = (float*)d_out;
  float* W   = (float*)d_ws;

  k_init   <<<128, 256, 0, stream>>>(W);
  k_pose   <<<1, 1, 0, stream>>>(pose_pred, pose_gt, W);
  k_medsel <<<4, 1024, 0, stream>>>(depth_pred, depth_gt, W);
  k_gather <<<64, 256, 0, stream>>>(points_pred, depth_gt, intr, W);
  k_cham   <<<dim3(64,4,2), 256, 0, stream>>>(W);
  k_chamfin<<<128, 256, 0, stream>>>(W);
  k_normdep<<<784, 256, 0, stream>>>(depth_pred, depth_gt, intr, W);
  k_final  <<<1, 1, 0, stream>>>(W, out);
}